// Round 3
// baseline (1308.837 us; speedup 1.0000x reference)
//
#include <hip/hip_runtime.h>
#include <math.h>

// LSTM: B=512, T=1000, I=64, H=50, gates 4H=200 torch order (i,f,g,o).
// One block (512 thr) per batch row. 8 lanes per hidden unit j:
//   lane 8j+2c+h : half h of gate class c (0=i,1=f,2=g,3=o), unit j.
// Even half holds W_ih row (16 float4 = 64 VGPR), odd half holds W_hh row
// (50 wts + 14 zeros, same 16 float4). Halves combine via shfl_xor(1);
// gates gather via shfl_xor(2)/(4) tree; lane 8j updates c (register) and
// writes h. One __syncthreads per step. x prefetched 2 steps ahead by
// wave 7 into a 4-slot LDS ring.

#define HSZ 50
#define ISZ 64
#define TSZ 1000

__global__ __launch_bounds__(512, 4) void lstm_fused(
    const float* __restrict__ x,      // [B, T, I]
    const float* __restrict__ W_ih,   // [4H, I]
    const float* __restrict__ W_hh,   // [4H, H]
    const float* __restrict__ b_ih,   // [4H]
    const float* __restrict__ b_hh,   // [4H]
    const float* __restrict__ W_out,  // [2, H]
    const float* __restrict__ b_out,  // [2]
    float* __restrict__ out)          // [B, 2]
{
    const int b   = blockIdx.x;
    const int tid = threadIdx.x;

    __shared__ __align__(256) float xs[4][ISZ];  // x ring: slot t&3
    __shared__ __align__(256) float hs[2][64];   // h double buffer, pad 50..63 = 0

    // ---- lane roles ----
    const int sub  = tid & 7;        // 0..7 within unit group
    const int half = sub & 1;        // 0 = x-part (W_ih), 1 = h-part (W_hh)
    const int cls  = sub >> 1;       // 0=i 1=f 2=g 3=o
    int j = tid >> 3; if (j > HSZ - 1) j = HSZ - 1;   // clamp for lanes >= 400
    const int G = cls * HSZ + j;     // gate row in [0,200)

    // ---- weights: 16 named float4 = 64 VGPRs ----
    float4 w0, w1, w2, w3, w4, w5, w6, w7, w8, w9, w10, w11, w12, w13, w14, w15;
    if (half == 0) {
        const float4* wi = (const float4*)(W_ih + G * ISZ);   // 256B rows, aligned
        w0 = wi[0];  w1 = wi[1];  w2  = wi[2];  w3  = wi[3];
        w4 = wi[4];  w5 = wi[5];  w6  = wi[6];  w7  = wi[7];
        w8 = wi[8];  w9 = wi[9];  w10 = wi[10]; w11 = wi[11];
        w12 = wi[12]; w13 = wi[13]; w14 = wi[14]; w15 = wi[15];
    } else {
        const float* wh = W_hh + G * HSZ;                     // 200B rows, scalar
#define LWH(k) make_float4(wh[4*(k)], wh[4*(k)+1], wh[4*(k)+2], wh[4*(k)+3])
        w0 = LWH(0);  w1 = LWH(1);  w2 = LWH(2);  w3 = LWH(3);
        w4 = LWH(4);  w5 = LWH(5);  w6 = LWH(6);  w7 = LWH(7);
        w8 = LWH(8);  w9 = LWH(9);  w10 = LWH(10); w11 = LWH(11);
#undef LWH
        w12 = make_float4(wh[48], wh[49], 0.0f, 0.0f);
        w13 = make_float4(0.f, 0.f, 0.f, 0.f);
        w14 = w13; w15 = w13;
    }
    const float bias = half ? b_hh[G] : b_ih[G];
    // activation: tanh(v) = 2*sigmoid(2v) - 1  ->  act = s2*sigmoid(s1*v)+s3
    const float s1 = (cls == 2) ? 2.0f : 1.0f;
    const float s2 = s1;
    const float s3 = (cls == 2) ? -1.0f : 0.0f;

    const float* xb = x + (size_t)b * (TSZ * ISZ);

    // init: x slots 0,1 ; h = 0 (incl pad)
    if (tid < 128) ((float*)xs)[tid] = xb[tid];
    if (tid < 128) ((float*)hs)[tid] = 0.0f;
    __syncthreads();

    float c_reg = 0.0f;

    for (int t = 0; t < TSZ; ++t) {
        if (tid < 400) {
            const float4* src4 = half ? (const float4*)&hs[t & 1][0]
                                      : (const float4*)&xs[t & 3][0];
            float a0 = bias, a1 = 0.0f, a2 = 0.0f, a3 = 0.0f;
#define STEP(k, W) { float4 v = src4[k];                       \
            a0 = fmaf(v.x, W.x, a0); a1 = fmaf(v.y, W.y, a1);  \
            a2 = fmaf(v.z, W.z, a2); a3 = fmaf(v.w, W.w, a3); }
            STEP(0,  w0)  STEP(1,  w1)  STEP(2,  w2)  STEP(3,  w3)
            STEP(4,  w4)  STEP(5,  w5)  STEP(6,  w6)  STEP(7,  w7)
            STEP(8,  w8)  STEP(9,  w9)  STEP(10, w10) STEP(11, w11)
            STEP(12, w12) STEP(13, w13) STEP(14, w14) STEP(15, w15)
#undef STEP
            float acc = (a0 + a1) + (a2 + a3);
            acc += __shfl_xor(acc, 1);                 // combine halves
            // activation (both halves compute identically)
            const float u   = s1 * acc;
            const float sig = 1.0f / (1.0f + __expf(-u));
            const float act = fmaf(s2, sig, s3);
            // gather the 4 gates of unit j to lanes 8j(+1)
            const float t2 = __shfl_xor(act, 2);
            const float t4 = __shfl_xor(act, 4);
            const float t6 = __shfl_xor(t2, 4);
            // on sub==0: act=i, t2=f, t4=g~, t6=o
            c_reg = fmaf(t2, c_reg, act * t4);
            const float tc = fmaf(2.0f, 1.0f / (1.0f + __expf(-2.0f * c_reg)), -1.0f);
            const float hv = t6 * tc;
            if (sub == 0) hs[(t + 1) & 1][j] = hv;
        } else if (tid >= 448) {
            const int l = tid - 448;                   // 0..63
            if (t + 2 < TSZ) xs[(t + 2) & 3][l] = xb[(size_t)(t + 2) * ISZ + l];
        }
        __syncthreads();
    }

    // out[b,k] = h_final . W_out[k] + b_out[k] ; h_final in hs[TSZ & 1]
    if (tid < 2) {
        float acc = b_out[tid];
        const float* wo = W_out + tid * HSZ;
        const float* hf = &hs[TSZ & 1][0];
        #pragma unroll
        for (int jj = 0; jj < HSZ; ++jj) acc = fmaf(hf[jj], wo[jj], acc);
        out[b * 2 + tid] = acc;
    }
}

extern "C" void kernel_launch(void* const* d_in, const int* in_sizes, int n_in,
                              void* d_out, int out_size, void* d_ws, size_t ws_size,
                              hipStream_t stream) {
    const float* x     = (const float*)d_in[0];
    const float* W_ih  = (const float*)d_in[1];
    const float* W_hh  = (const float*)d_in[2];
    const float* b_ih  = (const float*)d_in[3];
    const float* b_hh  = (const float*)d_in[4];
    const float* W_out = (const float*)d_in[5];
    const float* b_out = (const float*)d_in[6];
    float* out = (float*)d_out;

    const int B = in_sizes[0] / (TSZ * ISZ);   // 512
    hipLaunchKernelGGL(lstm_fused, dim3(B), dim3(512), 0, stream,
                       x, W_ih, W_hh, b_ih, b_hh, W_out, b_out, out);
}